// Round 5
// baseline (6906.927 us; speedup 1.0000x reference)
//
#include <hip/hip_runtime.h>
#include <hip/hip_bf16.h>

#define HID   512
#define SEQ   1024
#define GATES 2048       // 4*HID

// ---------------------------------------------------------------- helpers
__device__ __forceinline__ float sigm(float x) {
    return 1.f / (1.f + __expf(-x));
}
__device__ __forceinline__ float tanh_fast(float x) {
    float ax = fabsf(x);
    float e  = __expf(-2.f * ax);
    float t  = (1.f - e) * __builtin_amdgcn_rcpf(1.f + e);
    return copysignf(t, x);
}
// merge two per-lane partial-dot value streams: lanes with (lane&bit)==0 end up
// holding a's row, ==1 b's row, each summed with the partner lane's share.
__device__ __forceinline__ float merge2(float a, float b, int bit, int lane) {
    float keep = (lane & bit) ? b : a;
    float send = (lane & bit) ? a : b;
    return keep + __shfl_xor(send, bit, 64);
}

// ---------------------------------------------------------------- embedding
__global__ void embed_kernel(const int* __restrict__ wi, const int* __restrict__ pi,
                             const float* __restrict__ we, const float* __restrict__ pe,
                             float* __restrict__ x) {
    int i = blockIdx.x;          // token 0..1023
    int t = threadIdx.x;         // 128 threads
    const float* w = we + (size_t)wi[i] * 300;
    const float* p = pe + (size_t)pi[i] * 100;
    float* xo = x + (size_t)i * 400;
    for (int c = t; c < 300; c += 128) xo[c]       = w[c];
    for (int c = t; c < 100; c += 128) xo[300 + c] = p[c];
}

// ---------------------------------------------------------------- fp32 GEMM: C[M,N] = A[M,K] @ B[N,K]^T + bias[N]
__global__ __launch_bounds__(256)
void gemm_bias(const float* __restrict__ A, const float* __restrict__ B,
               const float* __restrict__ bias, float* __restrict__ C,
               int M, int N, int K, int lda, int ldb, int ldc) {
    __shared__ float As[64 * 17];
    __shared__ float Bs[64 * 17];
    const int tid  = threadIdx.x;
    const int bn   = blockIdx.x, bm = blockIdx.y;
    const int tj   = tid & 15, ti = tid >> 4;
    const int lrow = tid >> 2;
    const int lk4  = (tid & 3) << 2;
    float acc[4][4] = {};

    for (int kt = 0; kt < K; kt += 16) {
        float4 av = *(const float4*)(A + (size_t)(bm * 64 + lrow) * lda + kt + lk4);
        float4 bv = *(const float4*)(B + (size_t)(bn * 64 + lrow) * ldb + kt + lk4);
        As[lrow * 17 + lk4 + 0] = av.x; As[lrow * 17 + lk4 + 1] = av.y;
        As[lrow * 17 + lk4 + 2] = av.z; As[lrow * 17 + lk4 + 3] = av.w;
        Bs[lrow * 17 + lk4 + 0] = bv.x; Bs[lrow * 17 + lk4 + 1] = bv.y;
        Bs[lrow * 17 + lk4 + 2] = bv.z; Bs[lrow * 17 + lk4 + 3] = bv.w;
        __syncthreads();
        #pragma unroll
        for (int k = 0; k < 16; ++k) {
            float a0 = As[(ti * 4 + 0) * 17 + k];
            float a1 = As[(ti * 4 + 1) * 17 + k];
            float a2 = As[(ti * 4 + 2) * 17 + k];
            float a3 = As[(ti * 4 + 3) * 17 + k];
            float b0 = Bs[(tj * 4 + 0) * 17 + k];
            float b1 = Bs[(tj * 4 + 1) * 17 + k];
            float b2_ = Bs[(tj * 4 + 2) * 17 + k];
            float b3 = Bs[(tj * 4 + 3) * 17 + k];
            acc[0][0] = fmaf(a0, b0, acc[0][0]); acc[0][1] = fmaf(a0, b1, acc[0][1]);
            acc[0][2] = fmaf(a0, b2_, acc[0][2]); acc[0][3] = fmaf(a0, b3, acc[0][3]);
            acc[1][0] = fmaf(a1, b0, acc[1][0]); acc[1][1] = fmaf(a1, b1, acc[1][1]);
            acc[1][2] = fmaf(a1, b2_, acc[1][2]); acc[1][3] = fmaf(a1, b3, acc[1][3]);
            acc[2][0] = fmaf(a2, b0, acc[2][0]); acc[2][1] = fmaf(a2, b1, acc[2][1]);
            acc[2][2] = fmaf(a2, b2_, acc[2][2]); acc[2][3] = fmaf(a2, b3, acc[2][3]);
            acc[3][0] = fmaf(a3, b0, acc[3][0]); acc[3][1] = fmaf(a3, b1, acc[3][1]);
            acc[3][2] = fmaf(a3, b2_, acc[3][2]); acc[3][3] = fmaf(a3, b3, acc[3][3]);
        }
        __syncthreads();
    }
    const int n0 = bn * 64 + tj * 4;
    float bb0 = 0.f, bb1 = 0.f, bb2 = 0.f, bb3 = 0.f;
    if (bias) { bb0 = bias[n0]; bb1 = bias[n0 + 1]; bb2 = bias[n0 + 2]; bb3 = bias[n0 + 3]; }
    #pragma unroll
    for (int i = 0; i < 4; ++i) {
        float4 o;
        o.x = acc[i][0] + bb0; o.y = acc[i][1] + bb1;
        o.z = acc[i][2] + bb2; o.w = acc[i][3] + bb3;
        *(float4*)(C + (size_t)(bm * 64 + ti * 4 + i) * ldc + n0) = o;
    }
}

// ---------------------------------------------------------------- persistent bidirectional LSTM
// 512 single-wave blocks (64 thr). Blocks [0,256): forward; [256,512): reverse.
// Each WAVE owns 2 complete hidden units (8 full gate rows, K=512):
//   lane l holds Whh[row][c*64+l] (c=0..7) and h[c*64+l] — the matvec is 64
//   lane-private fmas, then a 6-stage merge-reduce (7 swizzles) leaves the
//   full dot of row (lane&7) in lane lane&7; lanes 0 and 4 compute the gates
//   and publish. h travels as (tag<<32|bits) relaxed AGENT atomics — the data
//   IS the flag; since the tag rides with the data, the poll IS the h load.
// No LDS state, no __syncthreads, no intra-block coupling whatsoever.
__global__ __launch_bounds__(64)
void lstm_wave(const float* __restrict__ Zf, const float* __restrict__ Zr,
               const float* __restrict__ WhhF, const float* __restrict__ WhhR,
               unsigned long long* __restrict__ Hpair, // [SEQ][2*HID] (tag|h)
               float* __restrict__ Hout,               // [SEQ][2*HID] plain fp32
               unsigned tagBase) {
    const int b   = blockIdx.x;
    const int dir = b >> 8;
    const int Ub  = (b & 255) * 2;          // first of this wave's 2 units
    const float* __restrict__ Z   = dir ? Zr   : Zf;
    const float* __restrict__ Whh = dir ? WhhR : WhhF;
    const int colOff = dir ? HID : 0;
    const int lane = threadIdx.x;

    // lane-private weights: w[j][c] = Whh[(j&3)*512 + Ub + (j>>2)][c*64+lane]
    // rows j=0..3 -> unit Ub gates i,f,g,o ; j=4..7 -> unit Ub+1
    float w[8][8];
    #pragma unroll
    for (int j = 0; j < 8; ++j) {
        const int row = (j & 3) * HID + Ub + (j >> 2);
        const float* wp = Whh + (size_t)row * HID + lane;
        #pragma unroll
        for (int c = 0; c < 8; ++c) w[j][c] = wp[c * 64];
    }

    const int  zsel  = lane >> 2;                       // 0/1 for lanes<8
    const bool isPub = (lane == 0) | (lane == 4);
    float cval = 0.f;                                   // cell of unit Ub+zsel (lanes 0,4)

    for (int s = 0; s < SEQ; ++s) {
        const int t = dir ? (SEQ - 1 - s) : s;

        // prefetch z for the epilogue (lanes 0..7 load; only 0,4 consumed)
        float z0 = 0.f, z1 = 0.f, z2 = 0.f, z3 = 0.f;
        if (lane < 8) {
            const float* zp = Z + (size_t)t * GATES + Ub + zsel;
            z0 = zp[0]; z1 = zp[512]; z2 = zp[1024]; z3 = zp[1536];
        }

        float h[8];
        if (s > 0) {
            const int tp = dir ? (t + 1) : (t - 1);
            const unsigned expTag = tagBase + (unsigned)s - 1u;
            const unsigned long long* hp = Hpair + (size_t)tp * (2 * HID) + colOff;
            unsigned long long v[8];
            for (;;) {
                #pragma unroll
                for (int c = 0; c < 8; ++c)
                    v[c] = __hip_atomic_load(hp + c * 64 + lane, __ATOMIC_RELAXED, __HIP_MEMORY_SCOPE_AGENT);
                int ok = 1;
                #pragma unroll
                for (int c = 0; c < 8; ++c) ok &= ((unsigned)(v[c] >> 32) == expTag);
                if (__all(ok)) break;
            }
            #pragma unroll
            for (int c = 0; c < 8; ++c) h[c] = __uint_as_float((unsigned)v[c]);
        } else {
            #pragma unroll
            for (int c = 0; c < 8; ++c) h[c] = 0.f;
        }

        // 8 lane-private partial dots (independent fma chains)
        float d[8];
        #pragma unroll
        for (int j = 0; j < 8; ++j) {
            float a = w[j][0] * h[0];
            a = fmaf(w[j][1], h[1], a);
            a = fmaf(w[j][2], h[2], a);
            a = fmaf(w[j][3], h[3], a);
            a = fmaf(w[j][4], h[4], a);
            a = fmaf(w[j][5], h[5], a);
            a = fmaf(w[j][6], h[6], a);
            a = fmaf(w[j][7], h[7], a);
            d[j] = a;
        }
        // merge-reduce: 8 values -> row (lane&7)'s full dot in lane (lane&7)
        float e0 = merge2(d[0], d[1], 1, lane);
        float e1 = merge2(d[2], d[3], 1, lane);
        float e2 = merge2(d[4], d[5], 1, lane);
        float e3 = merge2(d[6], d[7], 1, lane);
        float f0 = merge2(e0, e1, 2, lane);
        float f1 = merge2(e2, e3, 2, lane);
        float g  = merge2(f0, f1, 4, lane);
        g += __shfl_xor(g, 8, 64);
        g += __shfl_xor(g, 16, 64);
        g += __shfl_xor(g, 32, 64);
        // gather gates: lane 0 needs rows 0..3 (lanes 0..3); lane 4 rows 4..7
        float gf = __shfl_down(g, 1, 64);
        float gg_ = __shfl_down(g, 2, 64);
        float go = __shfl_down(g, 3, 64);

        if (isPub) {
            float zi = z0 + g;
            float zf = z1 + gf;
            float zg = z2 + gg_;
            float zo = z3 + go;
            float ig = sigm(zi), fg = sigm(zf), gt = tanh_fast(zg), og = sigm(zo);
            cval = fg * cval + ig * gt;
            float hv = og * tanh_fast(cval);
            const size_t oidx = (size_t)t * (2 * HID) + colOff + Ub + zsel;
            unsigned long long pk = ((unsigned long long)(tagBase + (unsigned)s) << 32)
                                  | (unsigned long long)__float_as_uint(hv);
            __hip_atomic_store(Hpair + oidx, pk, __ATOMIC_RELAXED, __HIP_MEMORY_SCOPE_AGENT);
            Hout[oidx] = hv;   // plain fp32 for downstream GEMMs
        }
    }
}

// ---------------------------------------------------------------- pairwise MLP scores
__global__ __launch_bounds__(256)
void pairwise_kernel(const float* __restrict__ Ah, const float* __restrict__ Bd,
                     const float* __restrict__ w2, const float* __restrict__ b2,
                     float* __restrict__ out) {
    __shared__ __align__(16) float at[16 * 260];
    __shared__ __align__(16) float bt[16 * 260];
    __shared__ __align__(16) float wl[256];
    const int tid = threadIdx.x;
    const int i0 = blockIdx.y * 16, j0 = blockIdx.x * 16;
    for (int u = tid; u < 16 * 256; u += 256) {
        int r = u >> 8, m = u & 255;
        at[r * 260 + m] = Ah[(size_t)(i0 + r) * 256 + m];
        bt[r * 260 + m] = Bd[(size_t)(j0 + r) * 256 + m];
    }
    wl[tid] = w2[tid];
    __syncthreads();
    const int tj = tid & 15, ti = tid >> 4;
    float acc = b2[0];
    #pragma unroll 2
    for (int m = 0; m < 256; m += 4) {
        float4 a4 = *(const float4*)&at[ti * 260 + m];
        float4 b4 = *(const float4*)&bt[tj * 260 + m];
        float4 w4 = *(const float4*)&wl[m];
        acc += tanh_fast(a4.x + b4.x) * w4.x;
        acc += tanh_fast(a4.y + b4.y) * w4.y;
        acc += tanh_fast(a4.z + b4.z) * w4.z;
        acc += tanh_fast(a4.w + b4.w) * w4.w;
    }
    out[(size_t)(i0 + ti) * 1024 + (j0 + tj)] = acc;
}

// ---------------------------------------------------------------- launch
extern "C" void kernel_launch(void* const* d_in, const int* in_sizes, int n_in,
                              void* d_out, int out_size, void* d_ws, size_t ws_size,
                              hipStream_t stream) {
    const int*   wi    = (const int*)  d_in[0];
    const int*   pi    = (const int*)  d_in[1];
    const float* we    = (const float*)d_in[2];
    const float* pe    = (const float*)d_in[3];
    const float* wih0f = (const float*)d_in[4];
    const float* whh0f = (const float*)d_in[5];
    const float* b0f   = (const float*)d_in[6];
    const float* wih0r = (const float*)d_in[7];
    const float* whh0r = (const float*)d_in[8];
    const float* b0r   = (const float*)d_in[9];
    const float* wih1f = (const float*)d_in[10];
    const float* whh1f = (const float*)d_in[11];
    const float* b1f   = (const float*)d_in[12];
    const float* wih1r = (const float*)d_in[13];
    const float* whh1r = (const float*)d_in[14];
    const float* b1r   = (const float*)d_in[15];
    const float* W1    = (const float*)d_in[16];
    const float* bmlp1 = (const float*)d_in[17];
    const float* w2    = (const float*)d_in[18];
    const float* b2    = (const float*)d_in[19];
    float* out = (float*)d_out;

    char* wsb = (char*)d_ws;
    float* x  = (float*)(wsb + 512);          // 1024*400
    float* zA = x  + (size_t)1024 * 400;      // 1024*2048
    float* zB = zA + (size_t)1024 * 2048;     // 1024*2048
    float* h0 = zB + (size_t)1024 * 2048;     // 1024*1024
    float* h1 = h0 + (size_t)1024 * 1024;     // 1024*1024
    float* aH = h1 + (size_t)1024 * 1024;     // 1024*256
    float* bD = aH + (size_t)1024 * 256;      // 1024*256
    unsigned long long* Hpair = (unsigned long long*)(bD + (size_t)1024 * 256); // 1024*1024 u64

    embed_kernel<<<dim3(1024), dim3(128), 0, stream>>>(wi, pi, we, pe, x);

    // layer-0 input projections: [1024,400] @ [2048,400]^T
    gemm_bias<<<dim3(32, 16), dim3(256), 0, stream>>>(x, wih0f, b0f, zA, 1024, 2048, 400, 400, 400, 2048);
    gemm_bias<<<dim3(32, 16), dim3(256), 0, stream>>>(x, wih0r, b0r, zB, 1024, 2048, 400, 400, 400, 2048);

    lstm_wave<<<dim3(512), dim3(64), 0, stream>>>(zA, zB, whh0f, whh0r, Hpair, h0, 1u);

    // layer-1 input projections: [1024,1024] @ [2048,1024]^T
    gemm_bias<<<dim3(32, 16), dim3(256), 0, stream>>>(h0, wih1f, b1f, zA, 1024, 2048, 1024, 1024, 1024, 2048);
    gemm_bias<<<dim3(32, 16), dim3(256), 0, stream>>>(h0, wih1r, b1r, zB, 1024, 2048, 1024, 1024, 1024, 2048);

    lstm_wave<<<dim3(512), dim3(64), 0, stream>>>(zA, zB, whh1f, whh1r, Hpair, h1, 8192u);

    // head/dep projections: [1024,1024] @ [256,1024]^T (bmlp1 folded into aH)
    gemm_bias<<<dim3(4, 16), dim3(256), 0, stream>>>(h1, W1,        bmlp1,   aH, 1024, 256, 1024, 1024, 2048, 256);
    gemm_bias<<<dim3(4, 16), dim3(256), 0, stream>>>(h1, W1 + 1024, nullptr, bD, 1024, 256, 1024, 1024, 2048, 256);

    pairwise_kernel<<<dim3(64, 64), dim3(256), 0, stream>>>(aH, bD, w2, b2, out);
}

// Round 6
// 5547.462 us; speedup vs baseline: 1.2451x; 1.2451x over previous
//
#include <hip/hip_runtime.h>
#include <hip/hip_bf16.h>

#define HID   512
#define SEQ   1024
#define GATES 2048       // 4*HID

// ---------------------------------------------------------------- helpers
__device__ __forceinline__ float sigm(float x) {
    return 1.f / (1.f + __expf(-x));
}
__device__ __forceinline__ float tanh_fast(float x) {
    float ax = fabsf(x);
    float e  = __expf(-2.f * ax);
    float t  = (1.f - e) * __builtin_amdgcn_rcpf(1.f + e);
    return copysignf(t, x);
}
// merge two per-lane partial-dot streams across lane-pairs differing in `bit`
__device__ __forceinline__ float merge2(float a, float b, int bit, int lane) {
    float keep = (lane & bit) ? b : a;
    float send = (lane & bit) ? a : b;
    return keep + __shfl_xor(send, bit, 64);
}

// ---------------------------------------------------------------- embedding
__global__ void embed_kernel(const int* __restrict__ wi, const int* __restrict__ pi,
                             const float* __restrict__ we, const float* __restrict__ pe,
                             float* __restrict__ x) {
    int i = blockIdx.x;          // token 0..1023
    int t = threadIdx.x;         // 128 threads
    const float* w = we + (size_t)wi[i] * 300;
    const float* p = pe + (size_t)pi[i] * 100;
    float* xo = x + (size_t)i * 400;
    for (int c = t; c < 300; c += 128) xo[c]       = w[c];
    for (int c = t; c < 100; c += 128) xo[300 + c] = p[c];
}

// ---------------------------------------------------------------- fp32 GEMM: C[M,N] = A[M,K] @ B[N,K]^T + bias[N]
__global__ __launch_bounds__(256)
void gemm_bias(const float* __restrict__ A, const float* __restrict__ B,
               const float* __restrict__ bias, float* __restrict__ C,
               int M, int N, int K, int lda, int ldb, int ldc) {
    __shared__ float As[64 * 17];
    __shared__ float Bs[64 * 17];
    const int tid  = threadIdx.x;
    const int bn   = blockIdx.x, bm = blockIdx.y;
    const int tj   = tid & 15, ti = tid >> 4;
    const int lrow = tid >> 2;
    const int lk4  = (tid & 3) << 2;
    float acc[4][4] = {};

    for (int kt = 0; kt < K; kt += 16) {
        float4 av = *(const float4*)(A + (size_t)(bm * 64 + lrow) * lda + kt + lk4);
        float4 bv = *(const float4*)(B + (size_t)(bn * 64 + lrow) * ldb + kt + lk4);
        As[lrow * 17 + lk4 + 0] = av.x; As[lrow * 17 + lk4 + 1] = av.y;
        As[lrow * 17 + lk4 + 2] = av.z; As[lrow * 17 + lk4 + 3] = av.w;
        Bs[lrow * 17 + lk4 + 0] = bv.x; Bs[lrow * 17 + lk4 + 1] = bv.y;
        Bs[lrow * 17 + lk4 + 2] = bv.z; Bs[lrow * 17 + lk4 + 3] = bv.w;
        __syncthreads();
        #pragma unroll
        for (int k = 0; k < 16; ++k) {
            float a0 = As[(ti * 4 + 0) * 17 + k];
            float a1 = As[(ti * 4 + 1) * 17 + k];
            float a2 = As[(ti * 4 + 2) * 17 + k];
            float a3 = As[(ti * 4 + 3) * 17 + k];
            float b0 = Bs[(tj * 4 + 0) * 17 + k];
            float b1 = Bs[(tj * 4 + 1) * 17 + k];
            float b2_ = Bs[(tj * 4 + 2) * 17 + k];
            float b3 = Bs[(tj * 4 + 3) * 17 + k];
            acc[0][0] = fmaf(a0, b0, acc[0][0]); acc[0][1] = fmaf(a0, b1, acc[0][1]);
            acc[0][2] = fmaf(a0, b2_, acc[0][2]); acc[0][3] = fmaf(a0, b3, acc[0][3]);
            acc[1][0] = fmaf(a1, b0, acc[1][0]); acc[1][1] = fmaf(a1, b1, acc[1][1]);
            acc[1][2] = fmaf(a1, b2_, acc[1][2]); acc[1][3] = fmaf(a1, b3, acc[1][3]);
            acc[2][0] = fmaf(a2, b0, acc[2][0]); acc[2][1] = fmaf(a2, b1, acc[2][1]);
            acc[2][2] = fmaf(a2, b2_, acc[2][2]); acc[2][3] = fmaf(a2, b3, acc[2][3]);
            acc[3][0] = fmaf(a3, b0, acc[3][0]); acc[3][1] = fmaf(a3, b1, acc[3][1]);
            acc[3][2] = fmaf(a3, b2_, acc[3][2]); acc[3][3] = fmaf(a3, b3, acc[3][3]);
        }
        __syncthreads();
    }
    const int n0 = bn * 64 + tj * 4;
    float bb0 = 0.f, bb1 = 0.f, bb2 = 0.f, bb3 = 0.f;
    if (bias) { bb0 = bias[n0]; bb1 = bias[n0 + 1]; bb2 = bias[n0 + 2]; bb3 = bias[n0 + 3]; }
    #pragma unroll
    for (int i = 0; i < 4; ++i) {
        float4 o;
        o.x = acc[i][0] + bb0; o.y = acc[i][1] + bb1;
        o.z = acc[i][2] + bb2; o.w = acc[i][3] + bb3;
        *(float4*)(C + (size_t)(bm * 64 + ti * 4 + i) * ldc + n0) = o;
    }
}

// ---------------------------------------------------------------- persistent bidirectional LSTM layer
// 64 WGs x 512 threads. WGs [0,32): forward; [32,64): reverse. Each WG owns 16
// hidden units; each of its 8 waves owns 2 complete units (8 full gate rows).
// Per step:
//   1. wave w polls ONLY chunk w of h(t-1): one (tag<<32|bits) u64 load/lane
//      per spin iteration — data IS the flag.
//   2. detected h chunk -> double-buffered LDS slab; one __syncthreads.
//   3. every wave reads all 512 h from LDS (8 conflict-free ds_reads/lane),
//      does 64 lane-private fmas (8 rows x 8 k-values, no readlane),
//      merge-reduces in 13 cross-lane ops; lanes 0,4 compute gates and
//      publish their unit immediately (no wave-0 serialization).
// Slab double-buffering removes the WAR hazard (barrier #s orders all reads of
// buf(s-1) before any wave can reach its write at step s+1), so no own-tag
// guard and no second barrier are needed.
__global__ __launch_bounds__(512)
void lstm_layer(const float* __restrict__ Zf, const float* __restrict__ Zr,
                const float* __restrict__ WhhF, const float* __restrict__ WhhR,
                unsigned long long* __restrict__ Hpair, // [SEQ][2*HID] (tag|h)
                float* __restrict__ Hout,               // [SEQ][2*HID] plain fp32
                unsigned tagBase) {
    const int dir = blockIdx.x >> 5;
    const int wg  = blockIdx.x & 31;
    const float* __restrict__ Z   = dir ? Zr   : Zf;
    const float* __restrict__ Whh = dir ? WhhR : WhhF;
    const int colOff = dir ? HID : 0;

    const int tid  = threadIdx.x;
    const int wave = tid >> 6;             // 0..7 = h chunk this wave polls
    const int lane = tid & 63;
    const int Ub   = wg * 16 + wave * 2;   // first of this wave's 2 units

    // lane-private weights: w[j][c] = Whh[(j&3)*512 + Ub + (j>>2)][c*64+lane]
    // rows j=0..3 -> unit Ub gates i,f,g,o ; j=4..7 -> unit Ub+1
    float w[8][8];
    #pragma unroll
    for (int j = 0; j < 8; ++j) {
        const int row = (j & 3) * HID + Ub + (j >> 2);
        const float* wp = Whh + (size_t)row * HID + lane;
        #pragma unroll
        for (int c = 0; c < 8; ++c) w[j][c] = wp[c * 64];
    }

    __shared__ float hsh[2][512];

    const int  zsel  = lane >> 2;                  // 0/1 (lanes<8)
    const bool isPub = (lane == 0) | (lane == 4);
    float cval = 0.f;                              // cell of unit Ub+zsel (lanes 0,4)

    for (int s = 0; s < SEQ; ++s) {
        const int t = dir ? (SEQ - 1 - s) : s;

        // prefetch z for the epilogue (lanes 0..7; only 0,4 consumed) — overlaps poll
        float z0 = 0.f, z1 = 0.f, z2 = 0.f, z3 = 0.f;
        if (lane < 8) {
            const float* zp = Z + (size_t)t * GATES + Ub + zsel;
            z0 = zp[0]; z1 = zp[512]; z2 = zp[1024]; z3 = zp[1536];
        }

        float* buf = hsh[s & 1];
        if (s > 0) {
            const int tp = dir ? (t + 1) : (t - 1);
            const unsigned expTag = tagBase + (unsigned)s - 1u;
            const unsigned long long* hp = Hpair + (size_t)tp * (2 * HID) + colOff + wave * 64;
            unsigned long long v;
            for (;;) {
                v = __hip_atomic_load(hp + lane, __ATOMIC_RELAXED, __HIP_MEMORY_SCOPE_AGENT);
                if (__all((unsigned)(v >> 32) == expTag)) break;
            }
            buf[wave * 64 + lane] = __uint_as_float((unsigned)v);
        } else {
            buf[wave * 64 + lane] = 0.f;
        }
        __syncthreads();

        // gather all 512 h values (conflict-free: lanes consecutive per read)
        float h[8];
        #pragma unroll
        for (int c = 0; c < 8; ++c) h[c] = buf[c * 64 + lane];

        // 8 lane-private partial dots (independent fma chains)
        float d[8];
        #pragma unroll
        for (int j = 0; j < 8; ++j) {
            float a = w[j][0] * h[0];
            a = fmaf(w[j][1], h[1], a);
            a = fmaf(w[j][2], h[2], a);
            a = fmaf(w[j][3], h[3], a);
            a = fmaf(w[j][4], h[4], a);
            a = fmaf(w[j][5], h[5], a);
            a = fmaf(w[j][6], h[6], a);
            a = fmaf(w[j][7], h[7], a);
            d[j] = a;
        }
        // merge-reduce: row (lane&7)'s full dot ends in lanes l with l&7==row
        float e0 = merge2(d[0], d[1], 1, lane);
        float e1 = merge2(d[2], d[3], 1, lane);
        float e2 = merge2(d[4], d[5], 1, lane);
        float e3 = merge2(d[6], d[7], 1, lane);
        float f0 = merge2(e0, e1, 2, lane);
        float f1 = merge2(e2, e3, 2, lane);
        float g  = merge2(f0, f1, 4, lane);
        g += __shfl_xor(g, 8, 64);
        g += __shfl_xor(g, 16, 64);
        g += __shfl_xor(g, 32, 64);
        // gate gather: lane 0 needs rows 0..3 (lanes 0..3); lane 4 rows 4..7
        float gf  = __shfl_down(g, 1, 64);
        float gg_ = __shfl_down(g, 2, 64);
        float go  = __shfl_down(g, 3, 64);

        if (isPub) {
            float zi = z0 + g;
            float zf = z1 + gf;
            float zg = z2 + gg_;
            float zo = z3 + go;
            float ig = sigm(zi), fg = sigm(zf), gt = tanh_fast(zg), og = sigm(zo);
            cval = fg * cval + ig * gt;
            float hv = og * tanh_fast(cval);
            const size_t oidx = (size_t)t * (2 * HID) + colOff + Ub + zsel;
            unsigned long long pk = ((unsigned long long)(tagBase + (unsigned)s) << 32)
                                  | (unsigned long long)__float_as_uint(hv);
            __hip_atomic_store(Hpair + oidx, pk, __ATOMIC_RELAXED, __HIP_MEMORY_SCOPE_AGENT);
            Hout[oidx] = hv;   // plain fp32 for downstream GEMMs
        }
    }
}

// ---------------------------------------------------------------- pairwise MLP scores
__global__ __launch_bounds__(256)
void pairwise_kernel(const float* __restrict__ Ah, const float* __restrict__ Bd,
                     const float* __restrict__ w2, const float* __restrict__ b2,
                     float* __restrict__ out) {
    __shared__ __align__(16) float at[16 * 260];
    __shared__ __align__(16) float bt[16 * 260];
    __shared__ __align__(16) float wl[256];
    const int tid = threadIdx.x;
    const int i0 = blockIdx.y * 16, j0 = blockIdx.x * 16;
    for (int u = tid; u < 16 * 256; u += 256) {
        int r = u >> 8, m = u & 255;
        at[r * 260 + m] = Ah[(size_t)(i0 + r) * 256 + m];
        bt[r * 260 + m] = Bd[(size_t)(j0 + r) * 256 + m];
    }
    wl[tid] = w2[tid];
    __syncthreads();
    const int tj = tid & 15, ti = tid >> 4;
    float acc = b2[0];
    #pragma unroll 2
    for (int m = 0; m < 256; m += 4) {
        float4 a4 = *(const float4*)&at[ti * 260 + m];
        float4 b4 = *(const float4*)&bt[tj * 260 + m];
        float4 w4 = *(const float4*)&wl[m];
        acc += tanh_fast(a4.x + b4.x) * w4.x;
        acc += tanh_fast(a4.y + b4.y) * w4.y;
        acc += tanh_fast(a4.z + b4.z) * w4.z;
        acc += tanh_fast(a4.w + b4.w) * w4.w;
    }
    out[(size_t)(i0 + ti) * 1024 + (j0 + tj)] = acc;
}

// ---------------------------------------------------------------- launch
extern "C" void kernel_launch(void* const* d_in, const int* in_sizes, int n_in,
                              void* d_out, int out_size, void* d_ws, size_t ws_size,
                              hipStream_t stream) {
    const int*   wi    = (const int*)  d_in[0];
    const int*   pi    = (const int*)  d_in[1];
    const float* we    = (const float*)d_in[2];
    const float* pe    = (const float*)d_in[3];
    const float* wih0f = (const float*)d_in[4];
    const float* whh0f = (const float*)d_in[5];
    const float* b0f   = (const float*)d_in[6];
    const float* wih0r = (const float*)d_in[7];
    const float* whh0r = (const float*)d_in[8];
    const float* b0r   = (const float*)d_in[9];
    const float* wih1f = (const float*)d_in[10];
    const float* whh1f = (const float*)d_in[11];
    const float* b1f   = (const float*)d_in[12];
    const float* wih1r = (const float*)d_in[13];
    const float* whh1r = (const float*)d_in[14];
    const float* b1r   = (const float*)d_in[15];
    const float* W1    = (const float*)d_in[16];
    const float* bmlp1 = (const float*)d_in[17];
    const float* w2    = (const float*)d_in[18];
    const float* b2    = (const float*)d_in[19];
    float* out = (float*)d_out;

    char* wsb = (char*)d_ws;
    float* x  = (float*)(wsb + 512);          // 1024*400
    float* zA = x  + (size_t)1024 * 400;      // 1024*2048
    float* zB = zA + (size_t)1024 * 2048;     // 1024*2048
    float* h0 = zB + (size_t)1024 * 2048;     // 1024*1024
    float* h1 = h0 + (size_t)1024 * 1024;     // 1024*1024
    float* aH = h1 + (size_t)1024 * 1024;     // 1024*256
    float* bD = aH + (size_t)1024 * 256;      // 1024*256
    unsigned long long* Hpair = (unsigned long long*)(bD + (size_t)1024 * 256); // 1024*1024 u64

    embed_kernel<<<dim3(1024), dim3(128), 0, stream>>>(wi, pi, we, pe, x);

    // layer-0 input projections: [1024,400] @ [2048,400]^T
    gemm_bias<<<dim3(32, 16), dim3(256), 0, stream>>>(x, wih0f, b0f, zA, 1024, 2048, 400, 400, 400, 2048);
    gemm_bias<<<dim3(32, 16), dim3(256), 0, stream>>>(x, wih0r, b0r, zB, 1024, 2048, 400, 400, 400, 2048);

    lstm_layer<<<dim3(64), dim3(512), 0, stream>>>(zA, zB, whh0f, whh0r, Hpair, h0, 1u);

    // layer-1 input projections: [1024,1024] @ [2048,1024]^T
    gemm_bias<<<dim3(32, 16), dim3(256), 0, stream>>>(h0, wih1f, b1f, zA, 1024, 2048, 1024, 1024, 1024, 2048);
    gemm_bias<<<dim3(32, 16), dim3(256), 0, stream>>>(h0, wih1r, b1r, zB, 1024, 2048, 1024, 1024, 1024, 2048);

    lstm_layer<<<dim3(64), dim3(512), 0, stream>>>(zA, zB, whh1f, whh1r, Hpair, h1, 8192u);

    // head/dep projections: [1024,1024] @ [256,1024]^T (bmlp1 folded into aH)
    gemm_bias<<<dim3(4, 16), dim3(256), 0, stream>>>(h1, W1,        bmlp1,   aH, 1024, 256, 1024, 1024, 2048, 256);
    gemm_bias<<<dim3(4, 16), dim3(256), 0, stream>>>(h1, W1 + 1024, nullptr, bD, 1024, 256, 1024, 1024, 2048, 256);

    pairwise_kernel<<<dim3(64, 64), dim3(256), 0, stream>>>(aH, bD, w2, b2, out);
}

// Round 7
// 3491.591 us; speedup vs baseline: 1.9782x; 1.5888x over previous
//
#include <hip/hip_runtime.h>
#include <hip/hip_bf16.h>

#define HID   512
#define SEQ   1024
#define GATES 2048       // 4*HID

// ---------------------------------------------------------------- helpers
__device__ __forceinline__ float sigm(float x) {
    return 1.f / (1.f + __expf(-x));
}
__device__ __forceinline__ float tanh_fast(float x) {
    float ax = fabsf(x);
    float e  = __expf(-2.f * ax);
    float t  = (1.f - e) * __builtin_amdgcn_rcpf(1.f + e);
    return copysignf(t, x);
}
__device__ __forceinline__ float bcast(float v, int l) {
    return __uint_as_float((unsigned)__builtin_amdgcn_readlane((int)__float_as_uint(v), l));
}

// ---------------------------------------------------------------- embedding
__global__ void embed_kernel(const int* __restrict__ wi, const int* __restrict__ pi,
                             const float* __restrict__ we, const float* __restrict__ pe,
                             float* __restrict__ x) {
    int i = blockIdx.x;          // token 0..1023
    int t = threadIdx.x;         // 128 threads
    const float* w = we + (size_t)wi[i] * 300;
    const float* p = pe + (size_t)pi[i] * 100;
    float* xo = x + (size_t)i * 400;
    for (int c = t; c < 300; c += 128) xo[c]       = w[c];
    for (int c = t; c < 100; c += 128) xo[300 + c] = p[c];
}

// ---------------------------------------------------------------- fp32 GEMM: C[M,N] = A[M,K] @ B[N,K]^T + bias[N]
// LDS tiles stored TRANSPOSED [k][row] (stride 68 => b128-aligned reads,
// <=2-way write conflicts which are free). Inner loop: 2x ds_read_b128 + 16 fma.
__global__ __launch_bounds__(256)
void gemm_bias(const float* __restrict__ A, const float* __restrict__ B,
               const float* __restrict__ bias, float* __restrict__ C,
               int M, int N, int K, int lda, int ldb, int ldc) {
    __shared__ __align__(16) float As[16 * 68];
    __shared__ __align__(16) float Bs[16 * 68];
    const int tid  = threadIdx.x;
    const int bn   = blockIdx.x, bm = blockIdx.y;
    const int tj   = tid & 15, ti = tid >> 4;
    const int lrow = tid >> 2;
    const int lk4  = (tid & 3) << 2;
    float acc[4][4] = {};

    for (int kt = 0; kt < K; kt += 16) {
        float4 av = *(const float4*)(A + (size_t)(bm * 64 + lrow) * lda + kt + lk4);
        float4 bv = *(const float4*)(B + (size_t)(bn * 64 + lrow) * ldb + kt + lk4);
        As[(lk4 + 0) * 68 + lrow] = av.x; As[(lk4 + 1) * 68 + lrow] = av.y;
        As[(lk4 + 2) * 68 + lrow] = av.z; As[(lk4 + 3) * 68 + lrow] = av.w;
        Bs[(lk4 + 0) * 68 + lrow] = bv.x; Bs[(lk4 + 1) * 68 + lrow] = bv.y;
        Bs[(lk4 + 2) * 68 + lrow] = bv.z; Bs[(lk4 + 3) * 68 + lrow] = bv.w;
        __syncthreads();
        #pragma unroll
        for (int k = 0; k < 16; ++k) {
            float4 a4 = *(const float4*)&As[k * 68 + ti * 4];
            float4 b4 = *(const float4*)&Bs[k * 68 + tj * 4];
            acc[0][0] = fmaf(a4.x, b4.x, acc[0][0]); acc[0][1] = fmaf(a4.x, b4.y, acc[0][1]);
            acc[0][2] = fmaf(a4.x, b4.z, acc[0][2]); acc[0][3] = fmaf(a4.x, b4.w, acc[0][3]);
            acc[1][0] = fmaf(a4.y, b4.x, acc[1][0]); acc[1][1] = fmaf(a4.y, b4.y, acc[1][1]);
            acc[1][2] = fmaf(a4.y, b4.z, acc[1][2]); acc[1][3] = fmaf(a4.y, b4.w, acc[1][3]);
            acc[2][0] = fmaf(a4.z, b4.x, acc[2][0]); acc[2][1] = fmaf(a4.z, b4.y, acc[2][1]);
            acc[2][2] = fmaf(a4.z, b4.z, acc[2][2]); acc[2][3] = fmaf(a4.z, b4.w, acc[2][3]);
            acc[3][0] = fmaf(a4.w, b4.x, acc[3][0]); acc[3][1] = fmaf(a4.w, b4.y, acc[3][1]);
            acc[3][2] = fmaf(a4.w, b4.z, acc[3][2]); acc[3][3] = fmaf(a4.w, b4.w, acc[3][3]);
        }
        __syncthreads();
    }
    const int n0 = bn * 64 + tj * 4;
    float bb0 = 0.f, bb1 = 0.f, bb2 = 0.f, bb3 = 0.f;
    if (bias) { bb0 = bias[n0]; bb1 = bias[n0 + 1]; bb2 = bias[n0 + 2]; bb3 = bias[n0 + 3]; }
    #pragma unroll
    for (int i = 0; i < 4; ++i) {
        float4 o;
        o.x = acc[i][0] + bb0; o.y = acc[i][1] + bb1;
        o.z = acc[i][2] + bb2; o.w = acc[i][3] + bb3;
        *(float4*)(C + (size_t)(bm * 64 + ti * 4 + i) * ldc + n0) = o;
    }
}

// ---------------------------------------------------------------- persistent bidirectional LSTM layer
// R3 structure (best measured) with a 1-load poll + double-buffered partials.
// 64 WGs x 512 threads. WGs [0,32): forward; [32,64): reverse. Each WG owns 16
// hidden units = 64 gate rows. lane = gate row (0..63), wave = 64-wide k-chunk
// (8 waves cover K=512). 64 weights/lane in registers.
// Poll: wave w spins on ONE (tag<<32|bits) u64 load/lane for chunk w — data IS
// the flag. Matvec: 64 readlane+fma (VALU-only, 4 acc chains). One barrier per
// step; wave 0 reduces partials + computes gates + publishes. `part` is
// double-buffered by step parity: barrier(s+1) orders wave-0's parity-p reads
// (step s) before any wave's parity-p writes (step s+2) — no own-tag guard.
__global__ __launch_bounds__(512)
void lstm_layer(const float* __restrict__ Zf, const float* __restrict__ Zr,
                const float* __restrict__ WhhF, const float* __restrict__ WhhR,
                unsigned long long* __restrict__ Hpair, // [SEQ][2*HID] (tag|h)
                float* __restrict__ Hout,               // [SEQ][2*HID] plain fp32
                unsigned tagBase) {
    const int dir = blockIdx.x >> 5;
    const int wg  = blockIdx.x & 31;
    const float* __restrict__ Z   = dir ? Zr   : Zf;
    const float* __restrict__ Whh = dir ? WhhR : WhhF;
    const int colOff = dir ? HID : 0;

    const int tid  = threadIdx.x;
    const int wave = tid >> 6;        // k-chunk 0..7 (h[64*wave .. +64))
    const int lane = tid & 63;        // local gate row 0..63
    const int g    = lane >> 4;       // gate 0..3 (i,f,g,o)
    const int jj   = lane & 15;       // local hidden unit 0..15
    const int grow = g * HID + wg * 16 + jj;   // row in Whh [2048 x 512]

    // this lane's 64 recurrent weights (k = wave*64 .. +64)
    float w[64];
    {
        const float4* wp = (const float4*)(Whh + (size_t)grow * HID + wave * 64);
        #pragma unroll
        for (int q = 0; q < 16; ++q) {
            float4 v = wp[q];
            w[4 * q] = v.x; w[4 * q + 1] = v.y; w[4 * q + 2] = v.z; w[4 * q + 3] = v.w;
        }
    }

    __shared__ float part[2][8 * 65];
    float cval = 0.f;                 // cell state (wave 0, lanes 0..15)

    for (int s = 0; s < SEQ; ++s) {
        const int t = dir ? (SEQ - 1 - s) : s;

        // wave 0 prefetches this row's input-projection z (overlaps the poll)
        float zin = 0.f;
        if (wave == 0) zin = Z[(size_t)t * GATES + grow];

        float acc = 0.f;
        if (s > 0) {
            const int tp = dir ? (t + 1) : (t - 1);
            const unsigned expTag = tagBase + (unsigned)s - 1u;
            const unsigned long long* hp = Hpair + (size_t)tp * (2 * HID) + colOff + wave * 64;
            unsigned long long v;
            for (;;) {
                v = __hip_atomic_load(hp + lane, __ATOMIC_RELAXED, __HIP_MEMORY_SCOPE_AGENT);
                if (__all((unsigned)(v >> 32) == expTag)) break;
            }
            float hv = __uint_as_float((unsigned)v);   // h[64*wave + lane]
            float a0 = 0.f, a1 = 0.f, a2 = 0.f, a3 = 0.f;
            #pragma unroll
            for (int m = 0; m < 64; m += 4) {
                a0 = fmaf(w[m + 0], bcast(hv, m + 0), a0);
                a1 = fmaf(w[m + 1], bcast(hv, m + 1), a1);
                a2 = fmaf(w[m + 2], bcast(hv, m + 2), a2);
                a3 = fmaf(w[m + 3], bcast(hv, m + 3), a3);
            }
            acc = (a0 + a1) + (a2 + a3);
        }
        part[s & 1][wave * 65 + lane] = acc;
        __syncthreads();   // waves 1..7 sprint ahead; wave 0 finishes the step

        if (wave == 0) {
            const float* pp = part[s & 1];
            float r = zin;
            #pragma unroll
            for (int c = 0; c < 8; ++c) r += pp[c * 65 + lane];
            // gather the 4 gates of unit jj (depth-1 shuffles)
            float zi = __shfl(r, jj);
            float zf = __shfl(r, 16 + jj);
            float zg = __shfl(r, 32 + jj);
            float zo = __shfl(r, 48 + jj);
            if (lane < 16) {
                float ig = sigm(zi), fg = sigm(zf), gg = tanh_fast(zg), og = sigm(zo);
                cval = fg * cval + ig * gg;
                float hv = og * tanh_fast(cval);
                const size_t oidx = (size_t)t * (2 * HID) + colOff + wg * 16 + lane;
                unsigned long long pk = ((unsigned long long)(tagBase + (unsigned)s) << 32)
                                      | (unsigned long long)__float_as_uint(hv);
                __hip_atomic_store(Hpair + oidx, pk, __ATOMIC_RELAXED, __HIP_MEMORY_SCOPE_AGENT);
                Hout[oidx] = hv;   // plain fp32 for downstream GEMMs
            }
        }
    }
}

// ---------------------------------------------------------------- pairwise MLP scores
__global__ __launch_bounds__(256)
void pairwise_kernel(const float* __restrict__ Ah, const float* __restrict__ Bd,
                     const float* __restrict__ w2, const float* __restrict__ b2,
                     float* __restrict__ out) {
    __shared__ __align__(16) float at[16 * 260];
    __shared__ __align__(16) float bt[16 * 260];
    __shared__ __align__(16) float wl[256];
    const int tid = threadIdx.x;
    const int i0 = blockIdx.y * 16, j0 = blockIdx.x * 16;
    for (int u = tid; u < 16 * 256; u += 256) {
        int r = u >> 8, m = u & 255;
        at[r * 260 + m] = Ah[(size_t)(i0 + r) * 256 + m];
        bt[r * 260 + m] = Bd[(size_t)(j0 + r) * 256 + m];
    }
    wl[tid] = w2[tid];
    __syncthreads();
    const int tj = tid & 15, ti = tid >> 4;
    float acc = b2[0];
    #pragma unroll 2
    for (int m = 0; m < 256; m += 4) {
        float4 a4 = *(const float4*)&at[ti * 260 + m];
        float4 b4 = *(const float4*)&bt[tj * 260 + m];
        float4 w4 = *(const float4*)&wl[m];
        acc += tanh_fast(a4.x + b4.x) * w4.x;
        acc += tanh_fast(a4.y + b4.y) * w4.y;
        acc += tanh_fast(a4.z + b4.z) * w4.z;
        acc += tanh_fast(a4.w + b4.w) * w4.w;
    }
    out[(size_t)(i0 + ti) * 1024 + (j0 + tj)] = acc;
}

// ---------------------------------------------------------------- launch
extern "C" void kernel_launch(void* const* d_in, const int* in_sizes, int n_in,
                              void* d_out, int out_size, void* d_ws, size_t ws_size,
                              hipStream_t stream) {
    const int*   wi    = (const int*)  d_in[0];
    const int*   pi    = (const int*)  d_in[1];
    const float* we    = (const float*)d_in[2];
    const float* pe    = (const float*)d_in[3];
    const float* wih0f = (const float*)d_in[4];
    const float* whh0f = (const float*)d_in[5];
    const float* b0f   = (const float*)d_in[6];
    const float* wih0r = (const float*)d_in[7];
    const float* whh0r = (const float*)d_in[8];
    const float* b0r   = (const float*)d_in[9];
    const float* wih1f = (const float*)d_in[10];
    const float* whh1f = (const float*)d_in[11];
    const float* b1f   = (const float*)d_in[12];
    const float* wih1r = (const float*)d_in[13];
    const float* whh1r = (const float*)d_in[14];
    const float* b1r   = (const float*)d_in[15];
    const float* W1    = (const float*)d_in[16];
    const float* bmlp1 = (const float*)d_in[17];
    const float* w2    = (const float*)d_in[18];
    const float* b2    = (const float*)d_in[19];
    float* out = (float*)d_out;

    char* wsb = (char*)d_ws;
    float* x  = (float*)(wsb + 512);          // 1024*400
    float* zA = x  + (size_t)1024 * 400;      // 1024*2048
    float* zB = zA + (size_t)1024 * 2048;     // 1024*2048
    float* h0 = zB + (size_t)1024 * 2048;     // 1024*1024
    float* h1 = h0 + (size_t)1024 * 1024;     // 1024*1024
    float* aH = h1 + (size_t)1024 * 1024;     // 1024*256
    float* bD = aH + (size_t)1024 * 256;      // 1024*256
    unsigned long long* Hpair = (unsigned long long*)(bD + (size_t)1024 * 256); // 1024*1024 u64

    embed_kernel<<<dim3(1024), dim3(128), 0, stream>>>(wi, pi, we, pe, x);

    // layer-0 input projections: [1024,400] @ [2048,400]^T
    gemm_bias<<<dim3(32, 16), dim3(256), 0, stream>>>(x, wih0f, b0f, zA, 1024, 2048, 400, 400, 400, 2048);
    gemm_bias<<<dim3(32, 16), dim3(256), 0, stream>>>(x, wih0r, b0r, zB, 1024, 2048, 400, 400, 400, 2048);

    lstm_layer<<<dim3(64), dim3(512), 0, stream>>>(zA, zB, whh0f, whh0r, Hpair, h0, 1u);

    // layer-1 input projections: [1024,1024] @ [2048,1024]^T
    gemm_bias<<<dim3(32, 16), dim3(256), 0, stream>>>(h0, wih1f, b1f, zA, 1024, 2048, 1024, 1024, 1024, 2048);
    gemm_bias<<<dim3(32, 16), dim3(256), 0, stream>>>(h0, wih1r, b1r, zB, 1024, 2048, 1024, 1024, 1024, 2048);

    lstm_layer<<<dim3(64), dim3(512), 0, stream>>>(zA, zB, whh1f, whh1r, Hpair, h1, 8192u);

    // head/dep projections: [1024,1024] @ [256,1024]^T (bmlp1 folded into aH)
    gemm_bias<<<dim3(4, 16), dim3(256), 0, stream>>>(h1, W1,        bmlp1,   aH, 1024, 256, 1024, 1024, 2048, 256);
    gemm_bias<<<dim3(4, 16), dim3(256), 0, stream>>>(h1, W1 + 1024, nullptr, bD, 1024, 256, 1024, 1024, 2048, 256);

    pairwise_kernel<<<dim3(64, 64), dim3(256), 0, stream>>>(aH, bD, w2, b2, out);
}